// Round 1
// 742.264 us; speedup vs baseline: 1.0020x; 1.0020x over previous
//
#include <hip/hip_runtime.h>
#include <hip/hip_bf16.h>
#include <math.h>
#include <float.h>

#define BB    64
#define CCH   256
#define KKE   1024
#define HWN   1024
#define NTOT  (BB*HWN)          // 65536
#define OUT_ELE (BB*CCH*HWN)    // 16777216
#define LOSS_OFF 0
#define OUT_OFF  1
#define PERP_OFF (1 + OUT_ELE)
#define ENC_OFF  (2 + OUT_ELE)   // byte off % 16 == 8 -> float2 stores only

// workspace layout (bytes)
#define WS_IDX    0               // int[65536]
#define WS_ANORM  262144          // float[65536]
#define WS_HIST   524288          // uint[1024]
#define WS_BNORM  528384          // float[1024]
#define WS_MISC   532480          // [0]=lossacc (float), [1]=counter (int)
#define WS_LIST   536576          // int[65536]
#define WS_EMBT   798720          // float[256*1024]
#define WS_EHI    1847296         // bf16[8][1024][32] chunked+swizzled LDS image
#define WS_ELO    2371584
#define WS_CD1    2895872         // float[8][65536]
#define WS_CK1    4993024         // int[8][65536]
#define WS_CD2    7090176         // float[8][65536]
#define WS_AHI    9187328         // bf16[8][65536][32] chunked+swizzled LDS image (33.55 MB)
#define WS_ALO    42741760        // same (33.55 MB)
// end 76296192 (~76.3 MB)

typedef __attribute__((ext_vector_type(4))) float f32x4;
typedef __attribute__((ext_vector_type(8))) short s16x8;

#define TAU 2e-4f

// async global->LDS, 16B per lane; LDS dest is wave-uniform base + lane*16
__device__ __forceinline__ void gload16(const short* g, void* l) {
    __builtin_amdgcn_global_load_lds(
        (const __attribute__((address_space(1))) unsigned int*)g,
        (__attribute__((address_space(3))) unsigned int*)l,
        16, 0, 0);
}

// merge two (d1,k1,d2) candidate sets; first-index tie-break
__device__ inline void merge_cand(float& d1, int& k1, float& d2,
                                  float od1, int ok1, float od2) {
    bool w = (od1 < d1) || (od1 == d1 && ok1 < k1);
    float loser_d1 = w ? d1 : od1;
    float winner_d2 = w ? od2 : d2;
    d2 = fminf(winner_d2, loser_d1);
    if (w) { d1 = od1; k1 = ok1; }
}

// ---------------- Kernel 1: transpose emb, ||e||^2 fp64, bf16 split of emb (swizzled
// LDS-image layout), zero accums
__global__ __launch_bounds__(256) void prep_kernel(const float* __restrict__ emb,
                                                   float* __restrict__ embT,
                                                   float* __restrict__ bnorm,
                                                   short* __restrict__ ehi,
                                                   short* __restrict__ elo,
                                                   unsigned int* __restrict__ hist,
                                                   float* __restrict__ misc) {
    const int k = blockIdx.x;     // 0..1023
    const int t = threadIdx.x;    // 0..255 = c
    float v = emb[k*CCH + t];
    embT[(size_t)t*KKE + k] = v;
    // bf16 split (RNE): v = hi + lo + eps(~2^-17 |v|)
    __hip_bfloat16 h = __float2bfloat16(v);
    float hf = __bfloat162float(h);
    __hip_bfloat16 l = __float2bfloat16(v - hf);
    // layout: [chunk=c>>5][k][swizzled c within 32]; unit' = unit ^ ((row>>1)&3)
    const int u  = (t & 31) >> 3;
    const int sw = (k >> 1) & 3;
    size_t eoff = (size_t)(t >> 5)*32768 + (size_t)k*32 + (size_t)((u ^ sw)*8 + (t & 7));
    ehi[eoff] = *(short*)&h;
    elo[eoff] = *(short*)&l;
    double sq = (double)v * (double)v;
    #pragma unroll
    for (int off = 32; off; off >>= 1) sq += __shfl_down(sq, off);
    __shared__ double wred[4];
    const int wave = t >> 6, lane = t & 63;
    if (lane == 0) wred[wave] = sq;
    __syncthreads();
    if (t == 0) bnorm[k] = (float)(wred[0] + wred[1] + wred[2] + wred[3]);
    if (blockIdx.x < 4) hist[blockIdx.x*256 + t] = 0u;
    if (blockIdx.x == 4 && t == 0) { misc[0] = 0.0f; ((int*)misc)[1] = 0; }
}

// ---------------- Kernel 1b: bf16 split of inp (once, not 8x) into chunked+swizzled
// LDS-image layout + fused ||x_n||^2 fp64 (same ascending-c order as before)
__global__ __launch_bounds__(256) void asplit_kernel(const float* __restrict__ inp,
                                                     short* __restrict__ ahi,
                                                     short* __restrict__ alo,
                                                     float* __restrict__ anorm) {
    const int t  = threadIdx.x;
    const int b  = blockIdx.y;
    const int hw = blockIdx.x * 256 + t;
    const int n  = b * HWN + hw;
    const float* src = inp + (size_t)b*CCH*HWN + hw;
    const int sw = (n >> 1) & 3;            // n&127 is the LDS row; bits 1..2 match
    double s = 0.0;
    for (int chunk = 0; chunk < 8; ++chunk) {
        s16x8 hs[4], ls[4];
        #pragma unroll
        for (int cc = 0; cc < 32; ++cc) {
            float v = src[(size_t)(chunk*32 + cc)*HWN];
            s += (double)v * (double)v;
            __hip_bfloat16 h = __float2bfloat16(v);
            float hf = __bfloat162float(h);
            __hip_bfloat16 l = __float2bfloat16(v - hf);
            hs[cc >> 3][cc & 7] = *(short*)&h;   // static reg-array indexing only
            ls[cc >> 3][cc & 7] = *(short*)&l;
        }
        const size_t obase = ((size_t)chunk*NTOT + (size_t)n) * 32;
        #pragma unroll
        for (int u = 0; u < 4; ++u) {           // XOR on the ADDRESS side (involution)
            *(s16x8*)&ahi[obase + (size_t)((u ^ sw) * 8)] = hs[u];
            *(s16x8*)&alo[obase + (size_t)((u ^ sw) * 8)] = ls[u];
        }
    }
    anorm[n] = (float)s;
}

// ---------------- Kernel 2: MFMA distance + per-k-block argmin candidates.
// grid (512 n-tiles, 8 k-tiles), 256 thr = 4 waves. Block tile 128n x 128k.
// Operands pre-split + pre-swizzled in global; staged via global_load_lds (no VALU,
// no ds_write). Frag reads use unit' = q ^ ((l15>>1)&3) -> uniform 8 lanes/bank-slot.
__global__ __launch_bounds__(256, 3) void argmin_mfma(const short* __restrict__ ahi,
                                                      const short* __restrict__ alo,
                                                      const short* __restrict__ ehi,
                                                      const short* __restrict__ elo,
                                                      const float* __restrict__ anorm,
                                                      const float* __restrict__ bnorm,
                                                      float* __restrict__ cd1,
                                                      int* __restrict__ ck1,
                                                      float* __restrict__ cd2) {
    __shared__ short smem[4][4096];   // Ahi, Alo, Bhi, Blo: 128 rows x 32 shorts (8 KB each)

    const int t    = threadIdx.x;
    const int w    = t >> 6;
    const int lane = t & 63;
    const int q    = lane >> 4;
    const int l15  = lane & 15;
    const int n0   = blockIdx.x * 128;
    const int k0   = blockIdx.y * 128;

    f32x4 acc[2][8];
    #pragma unroll
    for (int i = 0; i < 2; ++i)
        #pragma unroll
        for (int j = 0; j < 8; ++j) acc[i][j] = (f32x4){0.f,0.f,0.f,0.f};

    const int swu = (q ^ ((l15 >> 1) & 3)) << 4;   // same for all A/B frag rows used here
    const int ra0 = (w*32 + l15)*64 + swu;

    for (int chunk = 0; chunk < 8; ++chunk) {
        __syncthreads();   // all waves done reading previous chunk before overwrite
        {
            const short* as = ahi + (size_t)chunk*2097152 + (size_t)n0*32;
            const short* al = alo + (size_t)chunk*2097152 + (size_t)n0*32;
            const short* bs = ehi + (size_t)chunk*32768  + (size_t)k0*32;
            const short* bl = elo + (size_t)chunk*32768  + (size_t)k0*32;
            #pragma unroll
            for (int i = 0; i < 2; ++i) {
                const size_t so = (size_t)i*2048 + (size_t)t*8;   // shorts
                const int    lo = i*4096 + w*1024;                // bytes, wave-uniform base
                gload16(as + so, (char*)&smem[0][0] + lo);
                gload16(al + so, (char*)&smem[1][0] + lo);
                gload16(bs + so, (char*)&smem[2][0] + lo);
                gload16(bl + so, (char*)&smem[3][0] + lo);
            }
        }
        __syncthreads();   // compiler drains vmcnt(0) before barrier: tiles resident
        const char* LAh = (const char*)&smem[0][0];
        const char* LAl = (const char*)&smem[1][0];
        const char* LBh = (const char*)&smem[2][0];
        const char* LBl = (const char*)&smem[3][0];
        s16x8 afh0 = *(const s16x8*)(LAh + ra0);
        s16x8 afh1 = *(const s16x8*)(LAh + ra0 + 1024);
        s16x8 afl0 = *(const s16x8*)(LAl + ra0);
        s16x8 afl1 = *(const s16x8*)(LAl + ra0 + 1024);
        #pragma unroll
        for (int ct = 0; ct < 8; ++ct) {
            const int rb = (ct*16 + l15)*64 + swu;
            s16x8 bh = *(const s16x8*)(LBh + rb);
            s16x8 bl = *(const s16x8*)(LBl + rb);
            acc[0][ct] = __builtin_amdgcn_mfma_f32_16x16x32_bf16(afh0, bh, acc[0][ct], 0, 0, 0);
            acc[0][ct] = __builtin_amdgcn_mfma_f32_16x16x32_bf16(afh0, bl, acc[0][ct], 0, 0, 0);
            acc[0][ct] = __builtin_amdgcn_mfma_f32_16x16x32_bf16(afl0, bh, acc[0][ct], 0, 0, 0);
            acc[1][ct] = __builtin_amdgcn_mfma_f32_16x16x32_bf16(afh1, bh, acc[1][ct], 0, 0, 0);
            acc[1][ct] = __builtin_amdgcn_mfma_f32_16x16x32_bf16(afh1, bl, acc[1][ct], 0, 0, 0);
            acc[1][ct] = __builtin_amdgcn_mfma_f32_16x16x32_bf16(afl1, bh, acc[1][ct], 0, 0, 0);
        }
    }

    // ---- epilogue: d = (anorm+bnorm) - 2*dot; per-row best/second-best over 128 k
    float bnv[8];
    #pragma unroll
    for (int ct = 0; ct < 8; ++ct) bnv[ct] = bnorm[k0 + ct*16 + l15];

    #pragma unroll
    for (int rg = 0; rg < 2; ++rg) {
        #pragma unroll
        for (int reg = 0; reg < 4; ++reg) {
            const int n = n0 + w*32 + rg*16 + q*4 + reg;   // C/D: row = quad*4+reg
            const float a = anorm[n];
            float d1 = FLT_MAX, d2 = FLT_MAX; int k1 = 0;
            #pragma unroll
            for (int ct = 0; ct < 8; ++ct) {
                float s = a + bnv[ct];
                float d = s - 2.0f * acc[rg][ct][reg];
                int   k = k0 + ct*16 + l15;                // C/D: col = lane&15
                if (d < d1 || (d == d1 && k < k1)) { d2 = d1; d1 = d; k1 = k; }
                else d2 = fminf(d2, d);
            }
            #pragma unroll
            for (int off = 1; off < 16; off <<= 1) {
                float od1 = __shfl_xor(d1, off);
                int   ok1 = __shfl_xor(k1, off);
                float od2 = __shfl_xor(d2, off);
                merge_cand(d1, k1, d2, od1, ok1, od2);
            }
            if (l15 == 0) {
                const size_t o = (size_t)blockIdx.y*NTOT + n;
                cd1[o] = d1; ck1[o] = k1; cd2[o] = d2;
            }
        }
    }
}

// ---------------- Kernel 3: merge 8 k-block candidates, flag near-ties
__global__ __launch_bounds__(256) void reduce_kernel(const float* __restrict__ cd1,
                                                     const int* __restrict__ ck1,
                                                     const float* __restrict__ cd2,
                                                     int* __restrict__ idx,
                                                     int* __restrict__ list,
                                                     int* __restrict__ counter) {
    const int n = blockIdx.x*256 + threadIdx.x;
    float d1 = cd1[n]; int k1 = ck1[n]; float d2 = cd2[n];
    #pragma unroll
    for (int kb = 1; kb < 8; ++kb) {
        const size_t o = (size_t)kb*NTOT + n;
        merge_cand(d1, k1, d2, cd1[o], ck1[o], cd2[o]);
    }
    idx[n] = k1;
    if (d2 - d1 < TAU) {
        int p = atomicAdd(counter, 1);
        list[p] = n;
    }
}

// ---------------- Kernel 4: exact fp32 rescore (reference sequential-c semantics),
// coalesced via embT: at fixed c, thread t reads embT[c*1024 + kk*256 + t].
__global__ __launch_bounds__(256) void rescore_kernel(const float* __restrict__ inp,
                                                      const float* __restrict__ embT,
                                                      const float* __restrict__ anorm,
                                                      const float* __restrict__ bnorm,
                                                      const int* __restrict__ list,
                                                      const int* __restrict__ counter,
                                                      int* __restrict__ idx) {
    __shared__ float xs[256];
    __shared__ float rd[256];
    __shared__ int   rk[256];
    const int t = threadIdx.x;
    const int cnt = *counter;
    for (int f = blockIdx.x; f < cnt; f += gridDim.x) {
        const int n = list[f];
        const int b = n >> 10, hw = n & 1023;
        __syncthreads();
        xs[t] = inp[(size_t)b*CCH*HWN + (size_t)t*HWN + hw];
        __syncthreads();
        float dot0 = 0.f, dot1 = 0.f, dot2 = 0.f, dot3 = 0.f;
        #pragma unroll 4
        for (int c = 0; c < CCH; ++c) {
            const float xc = xs[c];
            const float* row = embT + (size_t)c*KKE + t;
            dot0 += xc * row[0];
            dot1 += xc * row[256];
            dot2 += xc * row[512];
            dot3 += xc * row[768];
        }
        const float a = anorm[n];
        float bd = FLT_MAX; int bk = 0;
        float dots[4] = {dot0, dot1, dot2, dot3};
        #pragma unroll
        for (int kk = 0; kk < 4; ++kk) {
            const int k = kk*256 + t;
            float s = a + bnorm[k];
            float d = s - 2.0f * dots[kk];
            if (d < bd || (d == bd && k < bk)) { bd = d; bk = k; }
        }
        rd[t] = bd; rk[t] = bk;
        __syncthreads();
        for (int stride = 128; stride; stride >>= 1) {
            if (t < stride) {
                float od = rd[t+stride]; int ok = rk[t+stride];
                if (od < rd[t] || (od == rd[t] && ok < rk[t])) { rd[t] = od; rk[t] = ok; }
            }
            __syncthreads();
        }
        if (t == 0) idx[n] = rk[0];
    }
}

// ---------------- Kernel 5: encodings one-hot + histogram (16 rows/block)
__global__ __launch_bounds__(256) void onehot_kernel(const int* __restrict__ idx,
                                                     float* __restrict__ enc,
                                                     unsigned int* __restrict__ hist) {
    const int t = threadIdx.x;
    const int j4 = t * 4;
    for (int r = 0; r < 16; ++r) {
        const int n = blockIdx.x*16 + r;
        const int k = idx[n];
        float2 v0 = {0.0f, 0.0f}, v1 = {0.0f, 0.0f};
        if (k == j4)     v0.x = 1.0f;
        if (k == j4 + 1) v0.y = 1.0f;
        if (k == j4 + 2) v1.x = 1.0f;
        if (k == j4 + 3) v1.y = 1.0f;
        float* row = enc + (size_t)n * KKE;
        *(float2*)&row[j4]     = v0;
        *(float2*)&row[j4 + 2] = v1;
        if (t == 0) atomicAdd(&hist[k], 1u);
    }
}

// ---------------- Kernel 6: out = gather(e), loss partials
__global__ __launch_bounds__(256) void out_loss_kernel(const float* __restrict__ inp,
                                                       const float* __restrict__ embT,
                                                       const int* __restrict__ idx,
                                                       float* __restrict__ out,
                                                       float* __restrict__ lossacc) {
    const int t = threadIdx.x;
    const size_t stride = (size_t)gridDim.x * 256;
    float lsum = 0.0f;
    for (size_t m = (size_t)blockIdx.x * 256 + t; m < (size_t)OUT_ELE; m += stride) {
        int hw = (int)(m & 1023);
        int c  = (int)((m >> 10) & 255);
        int b  = (int)(m >> 18);
        int k  = idx[b*HWN + hw];
        float e = embT[(size_t)c*KKE + k];
        float x = inp[m];
        out[m] = e;
        float df = e - x;
        lsum += df * df;
    }
    #pragma unroll
    for (int off = 32; off; off >>= 1) lsum += __shfl_down(lsum, off);
    __shared__ float wred[4];
    const int wave = t >> 6, lane = t & 63;
    if (lane == 0) wred[wave] = lsum;
    __syncthreads();
    if (t == 0) atomicAdd(lossacc, wred[0] + wred[1] + wred[2] + wred[3]);
}

// ---------------- Kernel 7: finalize
__global__ __launch_bounds__(1024) void final_kernel(const unsigned int* __restrict__ hist,
                                                     const float* __restrict__ lossacc,
                                                     float* __restrict__ d_out) {
    const int t = threadIdx.x;
    float p = (float)hist[t] * (1.0f / 65536.0f);
    float v = p * logf(p + 1e-10f);
    #pragma unroll
    for (int off = 32; off; off >>= 1) v += __shfl_down(v, off);
    __shared__ float wred[16];
    const int wave = t >> 6, lane = t & 63;
    if (lane == 0) wred[wave] = v;
    __syncthreads();
    if (t == 0) {
        float s = 0.0f;
        #pragma unroll
        for (int i = 0; i < 16; ++i) s += wred[i];
        d_out[PERP_OFF] = expf(-s);
        d_out[LOSS_OFF] = 1.25f * (*lossacc) * (1.0f / (float)OUT_ELE);
    }
}

extern "C" void kernel_launch(void* const* d_in, const int* in_sizes, int n_in,
                              void* d_out, int out_size, void* d_ws, size_t ws_size,
                              hipStream_t stream) {
    (void)in_sizes; (void)n_in; (void)out_size; (void)ws_size;
    const float* inp = (const float*)d_in[0];
    const float* emb = (const float*)d_in[1];
    float* out = (float*)d_out;
    char* ws = (char*)d_ws;
    int*          idx     = (int*)(ws + WS_IDX);
    float*        anorm   = (float*)(ws + WS_ANORM);
    unsigned int* hist    = (unsigned int*)(ws + WS_HIST);
    float*        bnorm   = (float*)(ws + WS_BNORM);
    float*        misc    = (float*)(ws + WS_MISC);
    int*          list    = (int*)(ws + WS_LIST);
    float*        embT    = (float*)(ws + WS_EMBT);
    short*        ehi     = (short*)(ws + WS_EHI);
    short*        elo     = (short*)(ws + WS_ELO);
    float*        cd1     = (float*)(ws + WS_CD1);
    int*          ck1     = (int*)(ws + WS_CK1);
    float*        cd2     = (float*)(ws + WS_CD2);
    short*        ahi     = (short*)(ws + WS_AHI);
    short*        alo     = (short*)(ws + WS_ALO);
    int*          counter = ((int*)misc) + 1;

    prep_kernel<<<dim3(KKE), dim3(256), 0, stream>>>(emb, embT, bnorm, ehi, elo, hist, misc);
    asplit_kernel<<<dim3(4, BB), dim3(256), 0, stream>>>(inp, ahi, alo, anorm);
    argmin_mfma<<<dim3(512, 8), dim3(256), 0, stream>>>(ahi, alo, ehi, elo, anorm, bnorm, cd1, ck1, cd2);
    reduce_kernel<<<dim3(256), dim3(256), 0, stream>>>(cd1, ck1, cd2, idx, list, counter);
    rescore_kernel<<<dim3(512), dim3(256), 0, stream>>>(inp, embT, anorm, bnorm, list, counter, idx);
    onehot_kernel<<<dim3(4096), dim3(256), 0, stream>>>(idx, out + ENC_OFF, hist);
    out_loss_kernel<<<dim3(4096), dim3(256), 0, stream>>>(inp, embT, idx, out + OUT_OFF, misc);
    final_kernel<<<dim3(1), dim3(1024), 0, stream>>>(hist, misc, out);
}

// Round 2
// 653.455 us; speedup vs baseline: 1.1382x; 1.1359x over previous
//
#include <hip/hip_runtime.h>
#include <hip/hip_bf16.h>
#include <math.h>
#include <float.h>

#define BB    64
#define CCH   256
#define KKE   1024
#define HWN   1024
#define NTOT  (BB*HWN)          // 65536
#define OUT_ELE (BB*CCH*HWN)    // 16777216
#define LOSS_OFF 0
#define OUT_OFF  1
#define PERP_OFF (1 + OUT_ELE)
#define ENC_OFF  (2 + OUT_ELE)   // byte off % 16 == 8

// workspace layout (bytes)
#define WS_IDX    0               // int[65536]
#define WS_ANORM  262144          // float[65536]
#define WS_HIST   524288          // uint[1024]
#define WS_BNORM  528384          // float[1024]
#define WS_MISC   532480          // [0]=lossacc (float), [1]=counter (int)
#define WS_LIST   536576          // int[65536]
#define WS_EMBT   798720          // float[256*1024]
#define WS_EHI    1847296         // bf16[8][1024][32] chunked+swizzled LDS image
#define WS_ELO    2371584
#define WS_CD1    2895872         // float[8][65536]
#define WS_CK1    4993024         // int[8][65536]
#define WS_CD2    7090176         // float[8][65536]
#define WS_AHI    9187328         // bf16[8][65536][32] chunked+swizzled LDS image (33.55 MB)
#define WS_ALO    42741760        // same (33.55 MB)
// end 76296192 (~76.3 MB)

typedef __attribute__((ext_vector_type(4))) float f32x4;
typedef __attribute__((ext_vector_type(8))) short s16x8;

#define TAU 2e-4f
#define RB  8                    // rescore batch size

// async global->LDS, 16B per lane; LDS dest is wave-uniform base + lane*16
__device__ __forceinline__ void gload16(const short* g, void* l) {
    __builtin_amdgcn_global_load_lds(
        (const __attribute__((address_space(1))) unsigned int*)g,
        (__attribute__((address_space(3))) unsigned int*)l,
        16, 0, 0);
}

// merge two (d1,k1,d2) candidate sets; first-index tie-break
__device__ inline void merge_cand(float& d1, int& k1, float& d2,
                                  float od1, int ok1, float od2) {
    bool w = (od1 < d1) || (od1 == d1 && ok1 < k1);
    float loser_d1 = w ? d1 : od1;
    float winner_d2 = w ? od2 : d2;
    d2 = fminf(winner_d2, loser_d1);
    if (w) { d1 = od1; k1 = ok1; }
}

// ---------------- Kernel 1: transpose emb, ||e||^2 fp64, bf16 split of emb (swizzled
// LDS-image layout), zero accums
__global__ __launch_bounds__(256) void prep_kernel(const float* __restrict__ emb,
                                                   float* __restrict__ embT,
                                                   float* __restrict__ bnorm,
                                                   short* __restrict__ ehi,
                                                   short* __restrict__ elo,
                                                   unsigned int* __restrict__ hist,
                                                   float* __restrict__ misc) {
    const int k = blockIdx.x;     // 0..1023
    const int t = threadIdx.x;    // 0..255 = c
    float v = emb[k*CCH + t];
    embT[(size_t)t*KKE + k] = v;
    // bf16 split (RNE): v = hi + lo + eps(~2^-17 |v|)
    __hip_bfloat16 h = __float2bfloat16(v);
    float hf = __bfloat162float(h);
    __hip_bfloat16 l = __float2bfloat16(v - hf);
    // layout: [chunk=c>>5][k][swizzled c within 32]; unit' = unit ^ ((row>>1)&3)
    const int u  = (t & 31) >> 3;
    const int sw = (k >> 1) & 3;
    size_t eoff = (size_t)(t >> 5)*32768 + (size_t)k*32 + (size_t)((u ^ sw)*8 + (t & 7));
    ehi[eoff] = *(short*)&h;
    elo[eoff] = *(short*)&l;
    double sq = (double)v * (double)v;
    #pragma unroll
    for (int off = 32; off; off >>= 1) sq += __shfl_down(sq, off);
    __shared__ double wred[4];
    const int wave = t >> 6, lane = t & 63;
    if (lane == 0) wred[wave] = sq;
    __syncthreads();
    if (t == 0) bnorm[k] = (float)(wred[0] + wred[1] + wred[2] + wred[3]);
    if (blockIdx.x < 4) hist[blockIdx.x*256 + t] = 0u;
    if (blockIdx.x == 4 && t == 0) { misc[0] = 0.0f; ((int*)misc)[1] = 0; }
}

// ---------------- Kernel 1b: bf16 split of inp into chunked+swizzled LDS image
// + fused ||x_n||^2 fp64 (same ascending-c order as before)
__global__ __launch_bounds__(256) void asplit_kernel(const float* __restrict__ inp,
                                                     short* __restrict__ ahi,
                                                     short* __restrict__ alo,
                                                     float* __restrict__ anorm) {
    const int t  = threadIdx.x;
    const int b  = blockIdx.y;
    const int hw = blockIdx.x * 256 + t;
    const int n  = b * HWN + hw;
    const float* src = inp + (size_t)b*CCH*HWN + hw;
    const int sw = (n >> 1) & 3;            // n&127 is the LDS row; bits 1..2 match
    double s = 0.0;
    for (int chunk = 0; chunk < 8; ++chunk) {
        s16x8 hs[4], ls[4];
        #pragma unroll
        for (int cc = 0; cc < 32; ++cc) {
            float v = src[(size_t)(chunk*32 + cc)*HWN];
            s += (double)v * (double)v;
            __hip_bfloat16 h = __float2bfloat16(v);
            float hf = __bfloat162float(h);
            __hip_bfloat16 l = __float2bfloat16(v - hf);
            hs[cc >> 3][cc & 7] = *(short*)&h;   // static reg-array indexing only
            ls[cc >> 3][cc & 7] = *(short*)&l;
        }
        const size_t obase = ((size_t)chunk*NTOT + (size_t)n) * 32;
        #pragma unroll
        for (int u = 0; u < 4; ++u) {           // XOR on the ADDRESS side (involution)
            *(s16x8*)&ahi[obase + (size_t)((u ^ sw) * 8)] = hs[u];
            *(s16x8*)&alo[obase + (size_t)((u ^ sw) * 8)] = ls[u];
        }
    }
    anorm[n] = (float)s;
}

// ---------------- Kernel 2: MFMA distance + per-k-block argmin candidates.
// grid (512 n-tiles, 8 k-tiles), 256 thr = 4 waves. Block tile 128n x 128k.
__global__ __launch_bounds__(256, 3) void argmin_mfma(const short* __restrict__ ahi,
                                                      const short* __restrict__ alo,
                                                      const short* __restrict__ ehi,
                                                      const short* __restrict__ elo,
                                                      const float* __restrict__ anorm,
                                                      const float* __restrict__ bnorm,
                                                      float* __restrict__ cd1,
                                                      int* __restrict__ ck1,
                                                      float* __restrict__ cd2) {
    __shared__ short smem[4][4096];   // Ahi, Alo, Bhi, Blo: 128 rows x 32 shorts (8 KB each)

    const int t    = threadIdx.x;
    const int w    = t >> 6;
    const int lane = t & 63;
    const int q    = lane >> 4;
    const int l15  = lane & 15;
    const int n0   = blockIdx.x * 128;
    const int k0   = blockIdx.y * 128;

    f32x4 acc[2][8];
    #pragma unroll
    for (int i = 0; i < 2; ++i)
        #pragma unroll
        for (int j = 0; j < 8; ++j) acc[i][j] = (f32x4){0.f,0.f,0.f,0.f};

    const int swu = (q ^ ((l15 >> 1) & 3)) << 4;   // same for all A/B frag rows used here
    const int ra0 = (w*32 + l15)*64 + swu;

    for (int chunk = 0; chunk < 8; ++chunk) {
        __syncthreads();   // all waves done reading previous chunk before overwrite
        {
            const short* as = ahi + (size_t)chunk*2097152 + (size_t)n0*32;
            const short* al = alo + (size_t)chunk*2097152 + (size_t)n0*32;
            const short* bs = ehi + (size_t)chunk*32768  + (size_t)k0*32;
            const short* bl = elo + (size_t)chunk*32768  + (size_t)k0*32;
            #pragma unroll
            for (int i = 0; i < 2; ++i) {
                const size_t so = (size_t)i*2048 + (size_t)t*8;   // shorts
                const int    lo = i*4096 + w*1024;                // bytes, wave-uniform base
                gload16(as + so, (char*)&smem[0][0] + lo);
                gload16(al + so, (char*)&smem[1][0] + lo);
                gload16(bs + so, (char*)&smem[2][0] + lo);
                gload16(bl + so, (char*)&smem[3][0] + lo);
            }
        }
        __syncthreads();   // compiler drains vmcnt(0) before barrier: tiles resident
        const char* LAh = (const char*)&smem[0][0];
        const char* LAl = (const char*)&smem[1][0];
        const char* LBh = (const char*)&smem[2][0];
        const char* LBl = (const char*)&smem[3][0];
        s16x8 afh0 = *(const s16x8*)(LAh + ra0);
        s16x8 afh1 = *(const s16x8*)(LAh + ra0 + 1024);
        s16x8 afl0 = *(const s16x8*)(LAl + ra0);
        s16x8 afl1 = *(const s16x8*)(LAl + ra0 + 1024);
        #pragma unroll
        for (int ct = 0; ct < 8; ++ct) {
            const int rb = (ct*16 + l15)*64 + swu;
            s16x8 bh = *(const s16x8*)(LBh + rb);
            s16x8 bl = *(const s16x8*)(LBl + rb);
            acc[0][ct] = __builtin_amdgcn_mfma_f32_16x16x32_bf16(afh0, bh, acc[0][ct], 0, 0, 0);
            acc[0][ct] = __builtin_amdgcn_mfma_f32_16x16x32_bf16(afh0, bl, acc[0][ct], 0, 0, 0);
            acc[0][ct] = __builtin_amdgcn_mfma_f32_16x16x32_bf16(afl0, bh, acc[0][ct], 0, 0, 0);
            acc[1][ct] = __builtin_amdgcn_mfma_f32_16x16x32_bf16(afh1, bh, acc[1][ct], 0, 0, 0);
            acc[1][ct] = __builtin_amdgcn_mfma_f32_16x16x32_bf16(afh1, bl, acc[1][ct], 0, 0, 0);
            acc[1][ct] = __builtin_amdgcn_mfma_f32_16x16x32_bf16(afl1, bh, acc[1][ct], 0, 0, 0);
        }
    }

    // ---- epilogue: d = (anorm+bnorm) - 2*dot; per-row best/second-best over 128 k
    float bnv[8];
    #pragma unroll
    for (int ct = 0; ct < 8; ++ct) bnv[ct] = bnorm[k0 + ct*16 + l15];

    #pragma unroll
    for (int rg = 0; rg < 2; ++rg) {
        #pragma unroll
        for (int reg = 0; reg < 4; ++reg) {
            const int n = n0 + w*32 + rg*16 + q*4 + reg;   // C/D: row = quad*4+reg
            const float a = anorm[n];
            float d1 = FLT_MAX, d2 = FLT_MAX; int k1 = 0;
            #pragma unroll
            for (int ct = 0; ct < 8; ++ct) {
                float s = a + bnv[ct];
                float d = s - 2.0f * acc[rg][ct][reg];
                int   k = k0 + ct*16 + l15;                // C/D: col = lane&15
                if (d < d1 || (d == d1 && k < k1)) { d2 = d1; d1 = d; k1 = k; }
                else d2 = fminf(d2, d);
            }
            #pragma unroll
            for (int off = 1; off < 16; off <<= 1) {
                float od1 = __shfl_xor(d1, off);
                int   ok1 = __shfl_xor(k1, off);
                float od2 = __shfl_xor(d2, off);
                merge_cand(d1, k1, d2, od1, ok1, od2);
            }
            if (l15 == 0) {
                const size_t o = (size_t)blockIdx.y*NTOT + n;
                cd1[o] = d1; ck1[o] = k1; cd2[o] = d2;
            }
        }
    }
}

// ---------------- Kernel 3: merge 8 k-block candidates, flag near-ties
__global__ __launch_bounds__(256) void reduce_kernel(const float* __restrict__ cd1,
                                                     const int* __restrict__ ck1,
                                                     const float* __restrict__ cd2,
                                                     int* __restrict__ idx,
                                                     int* __restrict__ list,
                                                     int* __restrict__ counter) {
    const int n = blockIdx.x*256 + threadIdx.x;
    float d1 = cd1[n]; int k1 = ck1[n]; float d2 = cd2[n];
    #pragma unroll
    for (int kb = 1; kb < 8; ++kb) {
        const size_t o = (size_t)kb*NTOT + n;
        merge_cand(d1, k1, d2, cd1[o], ck1[o], cd2[o]);
    }
    idx[n] = k1;
    if (d2 - d1 < TAU) {
        int p = atomicAdd(counter, 1);
        list[p] = n;
    }
}

// ---------------- Kernel 4: exact fp32 rescore, BATCHED: one embT stream serves RB
// items (L2 traffic / RB). Per-(item,k) arithmetic identical to the unbatched
// version: same sequential-c fp32 FMA chain, same d formula, same tie-break.
__global__ __launch_bounds__(256) void rescore_kernel(const float* __restrict__ inp,
                                                      const float* __restrict__ embT,
                                                      const float* __restrict__ anorm,
                                                      const float* __restrict__ bnorm,
                                                      const int* __restrict__ list,
                                                      const int* __restrict__ counter,
                                                      int* __restrict__ idx) {
    __shared__ float xs[RB][256];
    __shared__ float wd[RB][4];
    __shared__ int   wk[RB][4];
    __shared__ int   ls[RB];
    const int t = threadIdx.x;
    const int wave = t >> 6, lane = t & 63;
    const int cnt = *counter;
    const int ngrp = (cnt + RB - 1) / RB;
    // bnorm slice is group-invariant
    float bn[4];
    #pragma unroll
    for (int kk = 0; kk < 4; ++kk) bn[kk] = bnorm[kk*256 + t];

    for (int g = blockIdx.x; g < ngrp; g += gridDim.x) {
        const int base = g * RB;
        const int m = min(RB, cnt - base);
        __syncthreads();                       // protect xs/ls reuse across groups
        if (t < RB) ls[t] = list[base + ((t < m) ? t : 0)];   // pad with item 0
        __syncthreads();
        #pragma unroll
        for (int j = 0; j < RB; ++j) {
            const int n = ls[j];
            xs[j][t] = inp[(size_t)(n >> 10)*CCH*HWN + (size_t)t*HWN + (n & 1023)];
        }
        __syncthreads();
        float dots[RB][4];
        #pragma unroll
        for (int j = 0; j < RB; ++j)
            #pragma unroll
            for (int kk = 0; kk < 4; ++kk) dots[j][kk] = 0.f;
        #pragma unroll 4
        for (int c = 0; c < CCH; ++c) {
            const float* row = embT + (size_t)c*KKE + t;
            const float e0 = row[0], e1 = row[256], e2 = row[512], e3 = row[768];
            #pragma unroll
            for (int j = 0; j < RB; ++j) {
                const float xc = xs[j][c];
                dots[j][0] += xc * e0;
                dots[j][1] += xc * e1;
                dots[j][2] += xc * e2;
                dots[j][3] += xc * e3;
            }
        }
        #pragma unroll
        for (int j = 0; j < RB; ++j) {
            const float a = anorm[ls[j]];
            float bd = FLT_MAX; int bk = 0;
            #pragma unroll
            for (int kk = 0; kk < 4; ++kk) {
                const int k = kk*256 + t;
                float s = a + bn[kk];
                float d = s - 2.0f * dots[j][kk];
                if (d < bd || (d == bd && k < bk)) { bd = d; bk = k; }
            }
            #pragma unroll
            for (int off = 1; off < 64; off <<= 1) {
                float od = __shfl_xor(bd, off);
                int   ok = __shfl_xor(bk, off);
                if (od < bd || (od == bd && ok < bk)) { bd = od; bk = ok; }
            }
            if (lane == 0) { wd[j][wave] = bd; wk[j][wave] = bk; }
        }
        __syncthreads();
        if (t < m) {
            float bd = wd[t][0]; int bk = wk[t][0];
            #pragma unroll
            for (int wv = 1; wv < 4; ++wv) {
                float od = wd[t][wv]; int ok = wk[t][wv];
                if (od < bd || (od == bd && ok < bk)) { bd = od; bk = ok; }
            }
            idx[ls[t]] = bk;
        }
    }
}

// ---------------- Kernel 5 (fused): blocks [0,2048): encodings one-hot (aligned
// float4 window stores, 32 rows/block, idx preloaded) + histogram.
// blocks [2048,6144): out=gather(e) + loss partials (body identical to previous
// out_loss_kernel with gridDim 4096 -> same element mapping, same loss rounding).
#define ENC_BLK 2048
#define OL_BLK  4096
__global__ __launch_bounds__(256) void tail_kernel(const float* __restrict__ inp,
                                                   const float* __restrict__ embT,
                                                   const int* __restrict__ idx,
                                                   float* __restrict__ enc,
                                                   float* __restrict__ out,
                                                   unsigned int* __restrict__ hist,
                                                   float* __restrict__ lossacc) {
    const int t = threadIdx.x;
    if (blockIdx.x < ENC_BLK) {
        // ---- encodings: 32 rows per block
        const int n0 = blockIdx.x * 32;
        int kr[32];
        #pragma unroll
        for (int r4 = 0; r4 < 8; ++r4) {
            int4 kv = *(const int4*)&idx[n0 + r4*4];
            kr[r4*4+0] = kv.x; kr[r4*4+1] = kv.y; kr[r4*4+2] = kv.z; kr[r4*4+3] = kv.w;
        }
        const int j4 = t*4 + 2;          // float4 window [j4, j4+4) in [2,1022), t<255
        #pragma unroll 8
        for (int r = 0; r < 32; ++r) {
            const int k = kr[r];
            float* row = enc + (size_t)(n0 + r) * KKE;
            if (t < 255) {
                float4 v = {0.f,0.f,0.f,0.f};
                if (k == j4)     v.x = 1.f;
                if (k == j4 + 1) v.y = 1.f;
                if (k == j4 + 2) v.z = 1.f;
                if (k == j4 + 3) v.w = 1.f;
                *(float4*)&row[j4] = v;   // byte ≡ 0 mod 16
            } else {
                float2 h  = {0.f,0.f}, tl = {0.f,0.f};
                if (k == 0)    h.x  = 1.f;
                if (k == 1)    h.y  = 1.f;
                if (k == 1022) tl.x = 1.f;
                if (k == 1023) tl.y = 1.f;
                *(float2*)&row[0]    = h;    // byte ≡ 8 mod 16
                *(float2*)&row[1022] = tl;   // 8-aligned
            }
            if (t == 0) atomicAdd(&hist[k], 1u);
        }
    } else {
        // ---- out + loss (unchanged traversal)
        const size_t stride = (size_t)OL_BLK * 256;
        float lsum = 0.0f;
        for (size_t m = (size_t)(blockIdx.x - ENC_BLK) * 256 + t; m < (size_t)OUT_ELE; m += stride) {
            int hw = (int)(m & 1023);
            int c  = (int)((m >> 10) & 255);
            int b  = (int)(m >> 18);
            int k  = idx[b*HWN + hw];
            float e = embT[(size_t)c*KKE + k];
            float x = inp[m];
            out[m] = e;
            float df = e - x;
            lsum += df * df;
        }
        #pragma unroll
        for (int off = 32; off; off >>= 1) lsum += __shfl_down(lsum, off);
        __shared__ float wred[4];
        const int wave = t >> 6, lane = t & 63;
        if (lane == 0) wred[wave] = lsum;
        __syncthreads();
        if (t == 0) atomicAdd(lossacc, wred[0] + wred[1] + wred[2] + wred[3]);
    }
}

// ---------------- Kernel 7: finalize
__global__ __launch_bounds__(1024) void final_kernel(const unsigned int* __restrict__ hist,
                                                     const float* __restrict__ lossacc,
                                                     float* __restrict__ d_out) {
    const int t = threadIdx.x;
    float p = (float)hist[t] * (1.0f / 65536.0f);
    float v = p * logf(p + 1e-10f);
    #pragma unroll
    for (int off = 32; off; off >>= 1) v += __shfl_down(v, off);
    __shared__ float wred[16];
    const int wave = t >> 6, lane = t & 63;
    if (lane == 0) wred[wave] = v;
    __syncthreads();
    if (t == 0) {
        float s = 0.0f;
        #pragma unroll
        for (int i = 0; i < 16; ++i) s += wred[i];
        d_out[PERP_OFF] = expf(-s);
        d_out[LOSS_OFF] = 1.25f * (*lossacc) * (1.0f / (float)OUT_ELE);
    }
}

extern "C" void kernel_launch(void* const* d_in, const int* in_sizes, int n_in,
                              void* d_out, int out_size, void* d_ws, size_t ws_size,
                              hipStream_t stream) {
    (void)in_sizes; (void)n_in; (void)out_size; (void)ws_size;
    const float* inp = (const float*)d_in[0];
    const float* emb = (const float*)d_in[1];
    float* out = (float*)d_out;
    char* ws = (char*)d_ws;
    int*          idx     = (int*)(ws + WS_IDX);
    float*        anorm   = (float*)(ws + WS_ANORM);
    unsigned int* hist    = (unsigned int*)(ws + WS_HIST);
    float*        bnorm   = (float*)(ws + WS_BNORM);
    float*        misc    = (float*)(ws + WS_MISC);
    int*          list    = (int*)(ws + WS_LIST);
    float*        embT    = (float*)(ws + WS_EMBT);
    short*        ehi     = (short*)(ws + WS_EHI);
    short*        elo     = (short*)(ws + WS_ELO);
    float*        cd1     = (float*)(ws + WS_CD1);
    int*          ck1     = (int*)(ws + WS_CK1);
    float*        cd2     = (float*)(ws + WS_CD2);
    short*        ahi     = (short*)(ws + WS_AHI);
    short*        alo     = (short*)(ws + WS_ALO);
    int*          counter = ((int*)misc) + 1;

    prep_kernel<<<dim3(KKE), dim3(256), 0, stream>>>(emb, embT, bnorm, ehi, elo, hist, misc);
    asplit_kernel<<<dim3(4, BB), dim3(256), 0, stream>>>(inp, ahi, alo, anorm);
    argmin_mfma<<<dim3(512, 8), dim3(256), 0, stream>>>(ahi, alo, ehi, elo, anorm, bnorm, cd1, ck1, cd2);
    reduce_kernel<<<dim3(256), dim3(256), 0, stream>>>(cd1, ck1, cd2, idx, list, counter);
    rescore_kernel<<<dim3(512), dim3(256), 0, stream>>>(inp, embT, anorm, bnorm, list, counter, idx);
    tail_kernel<<<dim3(ENC_BLK + OL_BLK), dim3(256), 0, stream>>>(inp, embT, idx, out + ENC_OFF, out + OUT_OFF, hist, misc);
    final_kernel<<<dim3(1), dim3(1024), 0, stream>>>(hist, misc, out);
}

// Round 3
// 627.470 us; speedup vs baseline: 1.1853x; 1.0414x over previous
//
#include <hip/hip_runtime.h>
#include <hip/hip_bf16.h>
#include <math.h>
#include <float.h>

#define BB    64
#define CCH   256
#define KKE   1024
#define HWN   1024
#define NTOT  (BB*HWN)          // 65536
#define OUT_ELE (BB*CCH*HWN)    // 16777216
#define LOSS_OFF 0
#define OUT_OFF  1
#define PERP_OFF (1 + OUT_ELE)
#define ENC_OFF  (2 + OUT_ELE)   // byte off % 16 == 8

// workspace layout (bytes)
#define WS_IDX    0               // int[65536]
#define WS_ANORM  262144          // float[65536]
#define WS_HIST   524288          // uint[1024]
#define WS_BNORM  528384          // float[1024]
#define WS_MISC   532480          // [0]=lossacc (float), [1]=counter (int)
#define WS_LIST   536576          // int[65536]
#define WS_EMBT   798720          // float[256*1024]
#define WS_EHI    1847296         // bf16[8][1024][32] chunked+swizzled LDS image
#define WS_ELO    2371584
#define WS_CD1    2895872         // float[8][65536]
#define WS_CK1    4993024         // int[8][65536]
#define WS_CD2    7090176         // float[8][65536]
#define WS_AHI    9187328         // bf16[8][65536][32] chunked+swizzled LDS image (33.55 MB)
#define WS_ALO    42741760        // same (33.55 MB)
// end 76296192 (~76.3 MB)

typedef __attribute__((ext_vector_type(4))) float f32x4;
typedef __attribute__((ext_vector_type(8))) short s16x8;

#define TAU 2e-4f
#define RB  8                    // rescore batch size

// async global->LDS, 16B per lane; LDS dest is wave-uniform base + lane*16
__device__ __forceinline__ void gload16(const short* g, void* l) {
    __builtin_amdgcn_global_load_lds(
        (const __attribute__((address_space(1))) unsigned int*)g,
        (__attribute__((address_space(3))) unsigned int*)l,
        16, 0, 0);
}

// merge two (d1,k1,d2) candidate sets; first-index tie-break
__device__ inline void merge_cand(float& d1, int& k1, float& d2,
                                  float od1, int ok1, float od2) {
    bool w = (od1 < d1) || (od1 == d1 && ok1 < k1);
    float loser_d1 = w ? d1 : od1;
    float winner_d2 = w ? od2 : d2;
    d2 = fminf(winner_d2, loser_d1);
    if (w) { d1 = od1; k1 = ok1; }
}

// ---------------- Kernel 1: transpose emb, ||e||^2 fp64, bf16 split of emb (swizzled
// LDS-image layout), zero accums
__global__ __launch_bounds__(256) void prep_kernel(const float* __restrict__ emb,
                                                   float* __restrict__ embT,
                                                   float* __restrict__ bnorm,
                                                   short* __restrict__ ehi,
                                                   short* __restrict__ elo,
                                                   unsigned int* __restrict__ hist,
                                                   float* __restrict__ misc) {
    const int k = blockIdx.x;     // 0..1023
    const int t = threadIdx.x;    // 0..255 = c
    float v = emb[k*CCH + t];
    embT[(size_t)t*KKE + k] = v;
    // bf16 split (RNE): v = hi + lo + eps(~2^-17 |v|)
    __hip_bfloat16 h = __float2bfloat16(v);
    float hf = __bfloat162float(h);
    __hip_bfloat16 l = __float2bfloat16(v - hf);
    // layout: [chunk=c>>5][k][swizzled c within 32]; unit' = unit ^ ((row>>1)&3)
    const int u  = (t & 31) >> 3;
    const int sw = (k >> 1) & 3;
    size_t eoff = (size_t)(t >> 5)*32768 + (size_t)k*32 + (size_t)((u ^ sw)*8 + (t & 7));
    ehi[eoff] = *(short*)&h;
    elo[eoff] = *(short*)&l;
    double sq = (double)v * (double)v;
    #pragma unroll
    for (int off = 32; off; off >>= 1) sq += __shfl_down(sq, off);
    __shared__ double wred[4];
    const int wave = t >> 6, lane = t & 63;
    if (lane == 0) wred[wave] = sq;
    __syncthreads();
    if (t == 0) bnorm[k] = (float)(wred[0] + wred[1] + wred[2] + wred[3]);
    if (blockIdx.x < 4) hist[blockIdx.x*256 + t] = 0u;
    if (blockIdx.x == 4 && t == 0) { misc[0] = 0.0f; ((int*)misc)[1] = 0; }
}

// ---------------- Kernel 1b: bf16 split of inp into chunked+swizzled LDS image
// + fused ||x_n||^2 fp64 (same ascending-c order -> anorm bit-identical).
// v2: stage each 16 KB chunk image in LDS, store to global fully coalesced
// (1 KB per wave-instruction) instead of 64B-strided 16B stores.
__global__ __launch_bounds__(256) void asplit_kernel(const float* __restrict__ inp,
                                                     short* __restrict__ ahi,
                                                     short* __restrict__ alo,
                                                     float* __restrict__ anorm) {
    __shared__ short th[256*32];   // 16 KB hi staging
    __shared__ short tl[256*32];   // 16 KB lo staging
    const int t  = threadIdx.x;
    const int b  = blockIdx.y;
    const int hw = blockIdx.x * 256 + t;
    const int n  = b * HWN + hw;
    const int n0 = b * HWN + blockIdx.x * 256;
    const float* src = inp + (size_t)b*CCH*HWN + hw;
    const int sw = (t >> 1) & 3;   // == (n>>1)&3 since n0 % 256 == 0
    double s = 0.0;
    for (int chunk = 0; chunk < 8; ++chunk) {
        s16x8 hs[4], ls[4];
        #pragma unroll
        for (int cc = 0; cc < 32; ++cc) {
            float v = src[(size_t)(chunk*32 + cc)*HWN];
            s += (double)v * (double)v;
            __hip_bfloat16 h = __float2bfloat16(v);
            float hf = __bfloat162float(h);
            __hip_bfloat16 l = __float2bfloat16(v - hf);
            hs[cc >> 3][cc & 7] = *(short*)&h;   // static reg-array indexing only
            ls[cc >> 3][cc & 7] = *(short*)&l;
        }
        __syncthreads();   // previous chunk's LDS reads complete
        #pragma unroll
        for (int u = 0; u < 4; ++u) {   // bank-balanced: unit' = u^sw hits each bank 8x
            *(s16x8*)&th[t*32 + ((u ^ sw) << 3)] = hs[u];
            *(s16x8*)&tl[t*32 + ((u ^ sw) << 3)] = ls[u];
        }
        __syncthreads();
        const size_t obase = ((size_t)chunk*NTOT + (size_t)n0) * 32;  // shorts
        #pragma unroll
        for (int i = 0; i < 4; ++i) {   // coalesced: lane t -> bytes t*16 + i*4096
            const int so = i*2048 + t*8;
            *(s16x8*)&ahi[obase + so] = *(const s16x8*)&th[so];
            *(s16x8*)&alo[obase + so] = *(const s16x8*)&tl[so];
        }
    }
    anorm[n] = (float)s;
}

// ---------------- Kernel 2: MFMA distance + per-k-block argmin candidates.
// grid 4096 linear, 256 thr = 4 waves. Block tile 128n x 128k.
// v2: XCD-aware remap: the 8 k-tiles sharing one A-tile land on the SAME XCD in
// consecutive slots -> A (67 MB) is L2-served after first touch (was 537 MB L3).
__global__ __launch_bounds__(256, 3) void argmin_mfma(const short* __restrict__ ahi,
                                                      const short* __restrict__ alo,
                                                      const short* __restrict__ ehi,
                                                      const short* __restrict__ elo,
                                                      const float* __restrict__ anorm,
                                                      const float* __restrict__ bnorm,
                                                      float* __restrict__ cd1,
                                                      int* __restrict__ ck1,
                                                      float* __restrict__ cd2) {
    __shared__ short smem[4][4096];   // Ahi, Alo, Bhi, Blo: 128 rows x 32 shorts (8 KB each)

    const int t    = threadIdx.x;
    const int w    = t >> 6;
    const int lane = t & 63;
    const int q    = lane >> 4;
    const int l15  = lane & 15;
    const int L    = blockIdx.x;               // hw linear id; XCD = L % 8 (round-robin)
    const int bx   = (L & 7) + ((L >> 6) << 3);  // 0..511  (n-tile)
    const int by   = (L >> 3) & 7;               // 0..7    (k-tile)
    const int n0   = bx * 128;
    const int k0   = by * 128;

    f32x4 acc[2][8];
    #pragma unroll
    for (int i = 0; i < 2; ++i)
        #pragma unroll
        for (int j = 0; j < 8; ++j) acc[i][j] = (f32x4){0.f,0.f,0.f,0.f};

    const int swu = (q ^ ((l15 >> 1) & 3)) << 4;   // same for all A/B frag rows used here
    const int ra0 = (w*32 + l15)*64 + swu;

    for (int chunk = 0; chunk < 8; ++chunk) {
        __syncthreads();   // all waves done reading previous chunk before overwrite
        {
            const short* as = ahi + (size_t)chunk*2097152 + (size_t)n0*32;
            const short* al = alo + (size_t)chunk*2097152 + (size_t)n0*32;
            const short* bs = ehi + (size_t)chunk*32768  + (size_t)k0*32;
            const short* bl = elo + (size_t)chunk*32768  + (size_t)k0*32;
            #pragma unroll
            for (int i = 0; i < 2; ++i) {
                const size_t so = (size_t)i*2048 + (size_t)t*8;   // shorts
                const int    lo = i*4096 + w*1024;                // bytes, wave-uniform base
                gload16(as + so, (char*)&smem[0][0] + lo);
                gload16(al + so, (char*)&smem[1][0] + lo);
                gload16(bs + so, (char*)&smem[2][0] + lo);
                gload16(bl + so, (char*)&smem[3][0] + lo);
            }
        }
        __syncthreads();   // compiler drains vmcnt(0) before barrier: tiles resident
        const char* LAh = (const char*)&smem[0][0];
        const char* LAl = (const char*)&smem[1][0];
        const char* LBh = (const char*)&smem[2][0];
        const char* LBl = (const char*)&smem[3][0];
        s16x8 afh0 = *(const s16x8*)(LAh + ra0);
        s16x8 afh1 = *(const s16x8*)(LAh + ra0 + 1024);
        s16x8 afl0 = *(const s16x8*)(LAl + ra0);
        s16x8 afl1 = *(const s16x8*)(LAl + ra0 + 1024);
        #pragma unroll
        for (int ct = 0; ct < 8; ++ct) {
            const int rb = (ct*16 + l15)*64 + swu;
            s16x8 bh = *(const s16x8*)(LBh + rb);
            s16x8 bl = *(const s16x8*)(LBl + rb);
            acc[0][ct] = __builtin_amdgcn_mfma_f32_16x16x32_bf16(afh0, bh, acc[0][ct], 0, 0, 0);
            acc[0][ct] = __builtin_amdgcn_mfma_f32_16x16x32_bf16(afh0, bl, acc[0][ct], 0, 0, 0);
            acc[0][ct] = __builtin_amdgcn_mfma_f32_16x16x32_bf16(afl0, bh, acc[0][ct], 0, 0, 0);
            acc[1][ct] = __builtin_amdgcn_mfma_f32_16x16x32_bf16(afh1, bh, acc[1][ct], 0, 0, 0);
            acc[1][ct] = __builtin_amdgcn_mfma_f32_16x16x32_bf16(afh1, bl, acc[1][ct], 0, 0, 0);
            acc[1][ct] = __builtin_amdgcn_mfma_f32_16x16x32_bf16(afl1, bh, acc[1][ct], 0, 0, 0);
        }
    }

    // ---- epilogue: d = (anorm+bnorm) - 2*dot; per-row best/second-best over 128 k
    float bnv[8];
    #pragma unroll
    for (int ct = 0; ct < 8; ++ct) bnv[ct] = bnorm[k0 + ct*16 + l15];

    #pragma unroll
    for (int rg = 0; rg < 2; ++rg) {
        #pragma unroll
        for (int reg = 0; reg < 4; ++reg) {
            const int n = n0 + w*32 + rg*16 + q*4 + reg;   // C/D: row = quad*4+reg
            const float a = anorm[n];
            float d1 = FLT_MAX, d2 = FLT_MAX; int k1 = 0;
            #pragma unroll
            for (int ct = 0; ct < 8; ++ct) {
                float s = a + bnv[ct];
                float d = s - 2.0f * acc[rg][ct][reg];
                int   k = k0 + ct*16 + l15;                // C/D: col = lane&15
                if (d < d1 || (d == d1 && k < k1)) { d2 = d1; d1 = d; k1 = k; }
                else d2 = fminf(d2, d);
            }
            #pragma unroll
            for (int off = 1; off < 16; off <<= 1) {
                float od1 = __shfl_xor(d1, off);
                int   ok1 = __shfl_xor(k1, off);
                float od2 = __shfl_xor(d2, off);
                merge_cand(d1, k1, d2, od1, ok1, od2);
            }
            if (l15 == 0) {
                const size_t o = (size_t)by*NTOT + n;
                cd1[o] = d1; ck1[o] = k1; cd2[o] = d2;
            }
        }
    }
}

// ---------------- Kernel 3: merge 8 k-block candidates, flag near-ties
__global__ __launch_bounds__(256) void reduce_kernel(const float* __restrict__ cd1,
                                                     const int* __restrict__ ck1,
                                                     const float* __restrict__ cd2,
                                                     int* __restrict__ idx,
                                                     int* __restrict__ list,
                                                     int* __restrict__ counter) {
    const int n = blockIdx.x*256 + threadIdx.x;
    float d1 = cd1[n]; int k1 = ck1[n]; float d2 = cd2[n];
    #pragma unroll
    for (int kb = 1; kb < 8; ++kb) {
        const size_t o = (size_t)kb*NTOT + n;
        merge_cand(d1, k1, d2, cd1[o], ck1[o], cd2[o]);
    }
    idx[n] = k1;
    if (d2 - d1 < TAU) {
        int p = atomicAdd(counter, 1);
        list[p] = n;
    }
}

// ---------------- Kernel 4: exact fp32 rescore, BATCHED: one embT stream serves RB
// items (L2 traffic / RB). Per-(item,k) arithmetic identical to the unbatched
// version: same sequential-c fp32 FMA chain, same d formula, same tie-break.
__global__ __launch_bounds__(256) void rescore_kernel(const float* __restrict__ inp,
                                                      const float* __restrict__ embT,
                                                      const float* __restrict__ anorm,
                                                      const float* __restrict__ bnorm,
                                                      const int* __restrict__ list,
                                                      const int* __restrict__ counter,
                                                      int* __restrict__ idx) {
    __shared__ float xs[RB][256];
    __shared__ float wd[RB][4];
    __shared__ int   wk[RB][4];
    __shared__ int   ls[RB];
    const int t = threadIdx.x;
    const int wave = t >> 6, lane = t & 63;
    const int cnt = *counter;
    const int ngrp = (cnt + RB - 1) / RB;
    // bnorm slice is group-invariant
    float bn[4];
    #pragma unroll
    for (int kk = 0; kk < 4; ++kk) bn[kk] = bnorm[kk*256 + t];

    for (int g = blockIdx.x; g < ngrp; g += gridDim.x) {
        const int base = g * RB;
        const int m = min(RB, cnt - base);
        __syncthreads();                       // protect xs/ls reuse across groups
        if (t < RB) ls[t] = list[base + ((t < m) ? t : 0)];   // pad with item 0
        __syncthreads();
        #pragma unroll
        for (int j = 0; j < RB; ++j) {
            const int n = ls[j];
            xs[j][t] = inp[(size_t)(n >> 10)*CCH*HWN + (size_t)t*HWN + (n & 1023)];
        }
        __syncthreads();
        float dots[RB][4];
        #pragma unroll
        for (int j = 0; j < RB; ++j)
            #pragma unroll
            for (int kk = 0; kk < 4; ++kk) dots[j][kk] = 0.f;
        #pragma unroll 4
        for (int c = 0; c < CCH; ++c) {
            const float* row = embT + (size_t)c*KKE + t;
            const float e0 = row[0], e1 = row[256], e2 = row[512], e3 = row[768];
            #pragma unroll
            for (int j = 0; j < RB; ++j) {
                const float xc = xs[j][c];
                dots[j][0] += xc * e0;
                dots[j][1] += xc * e1;
                dots[j][2] += xc * e2;
                dots[j][3] += xc * e3;
            }
        }
        #pragma unroll
        for (int j = 0; j < RB; ++j) {
            const float a = anorm[ls[j]];
            float bd = FLT_MAX; int bk = 0;
            #pragma unroll
            for (int kk = 0; kk < 4; ++kk) {
                const int k = kk*256 + t;
                float s = a + bn[kk];
                float d = s - 2.0f * dots[j][kk];
                if (d < bd || (d == bd && k < bk)) { bd = d; bk = k; }
            }
            #pragma unroll
            for (int off = 1; off < 64; off <<= 1) {
                float od = __shfl_xor(bd, off);
                int   ok = __shfl_xor(bk, off);
                if (od < bd || (od == bd && ok < bk)) { bd = od; bk = ok; }
            }
            if (lane == 0) { wd[j][wave] = bd; wk[j][wave] = bk; }
        }
        __syncthreads();
        if (t < m) {
            float bd = wd[t][0]; int bk = wk[t][0];
            #pragma unroll
            for (int wv = 1; wv < 4; ++wv) {
                float od = wd[t][wv]; int ok = wk[t][wv];
                if (od < bd || (od == bd && ok < bk)) { bd = od; bk = ok; }
            }
            idx[ls[t]] = bk;
        }
    }
}

// ---------------- Kernel 5 (fused): blocks [0,2048): encodings one-hot (aligned
// float4 window stores, 32 rows/block, idx preloaded) + histogram.
// blocks [2048,6144): out=gather(e) + loss partials.
#define ENC_BLK 2048
#define OL_BLK  4096
__global__ __launch_bounds__(256) void tail_kernel(const float* __restrict__ inp,
                                                   const float* __restrict__ embT,
                                                   const int* __restrict__ idx,
                                                   float* __restrict__ enc,
                                                   float* __restrict__ out,
                                                   unsigned int* __restrict__ hist,
                                                   float* __restrict__ lossacc) {
    const int t = threadIdx.x;
    if (blockIdx.x < ENC_BLK) {
        // ---- encodings: 32 rows per block
        const int n0 = blockIdx.x * 32;
        int kr[32];
        #pragma unroll
        for (int r4 = 0; r4 < 8; ++r4) {
            int4 kv = *(const int4*)&idx[n0 + r4*4];
            kr[r4*4+0] = kv.x; kr[r4*4+1] = kv.y; kr[r4*4+2] = kv.z; kr[r4*4+3] = kv.w;
        }
        const int j4 = t*4 + 2;          // float4 window [j4, j4+4) in [2,1022), t<255
        #pragma unroll 8
        for (int r = 0; r < 32; ++r) {
            const int k = kr[r];
            float* row = enc + (size_t)(n0 + r) * KKE;
            if (t < 255) {
                float4 v = {0.f,0.f,0.f,0.f};
                if (k == j4)     v.x = 1.f;
                if (k == j4 + 1) v.y = 1.f;
                if (k == j4 + 2) v.z = 1.f;
                if (k == j4 + 3) v.w = 1.f;
                *(float4*)&row[j4] = v;   // byte ≡ 0 mod 16
            } else {
                float2 h  = {0.f,0.f}, tl = {0.f,0.f};
                if (k == 0)    h.x  = 1.f;
                if (k == 1)    h.y  = 1.f;
                if (k == 1022) tl.x = 1.f;
                if (k == 1023) tl.y = 1.f;
                *(float2*)&row[0]    = h;    // byte ≡ 8 mod 16
                *(float2*)&row[1022] = tl;   // 8-aligned
            }
            if (t == 0) atomicAdd(&hist[k], 1u);
        }
    } else {
        // ---- out + loss (unchanged traversal)
        const size_t stride = (size_t)OL_BLK * 256;
        float lsum = 0.0f;
        for (size_t m = (size_t)(blockIdx.x - ENC_BLK) * 256 + t; m < (size_t)OUT_ELE; m += stride) {
            int hw = (int)(m & 1023);
            int c  = (int)((m >> 10) & 255);
            int b  = (int)(m >> 18);
            int k  = idx[b*HWN + hw];
            float e = embT[(size_t)c*KKE + k];
            float x = inp[m];
            out[m] = e;
            float df = e - x;
            lsum += df * df;
        }
        #pragma unroll
        for (int off = 32; off; off >>= 1) lsum += __shfl_down(lsum, off);
        __shared__ float wred[4];
        const int wave = t >> 6, lane = t & 63;
        if (lane == 0) wred[wave] = lsum;
        __syncthreads();
        if (t == 0) atomicAdd(lossacc, wred[0] + wred[1] + wred[2] + wred[3]);
    }
}

// ---------------- Kernel 7: finalize
__global__ __launch_bounds__(1024) void final_kernel(const unsigned int* __restrict__ hist,
                                                     const float* __restrict__ lossacc,
                                                     float* __restrict__ d_out) {
    const int t = threadIdx.x;
    float p = (float)hist[t] * (1.0f / 65536.0f);
    float v = p * logf(p + 1e-10f);
    #pragma unroll
    for (int off = 32; off; off >>= 1) v += __shfl_down(v, off);
    __shared__ float wred[16];
    const int wave = t >> 6, lane = t & 63;
    if (lane == 0) wred[wave] = v;
    __syncthreads();
    if (t == 0) {
        float s = 0.0f;
        #pragma unroll
        for (int i = 0; i < 16; ++i) s += wred[i];
        d_out[PERP_OFF] = expf(-s);
        d_out[LOSS_OFF] = 1.25f * (*lossacc) * (1.0f / (float)OUT_ELE);
    }
}

extern "C" void kernel_launch(void* const* d_in, const int* in_sizes, int n_in,
                              void* d_out, int out_size, void* d_ws, size_t ws_size,
                              hipStream_t stream) {
    (void)in_sizes; (void)n_in; (void)out_size; (void)ws_size;
    const float* inp = (const float*)d_in[0];
    const float* emb = (const float*)d_in[1];
    float* out = (float*)d_out;
    char* ws = (char*)d_ws;
    int*          idx     = (int*)(ws + WS_IDX);
    float*        anorm   = (float*)(ws + WS_ANORM);
    unsigned int* hist    = (unsigned int*)(ws + WS_HIST);
    float*        bnorm   = (float*)(ws + WS_BNORM);
    float*        misc    = (float*)(ws + WS_MISC);
    int*          list    = (int*)(ws + WS_LIST);
    float*        embT    = (float*)(ws + WS_EMBT);
    short*        ehi     = (short*)(ws + WS_EHI);
    short*        elo     = (short*)(ws + WS_ELO);
    float*        cd1     = (float*)(ws + WS_CD1);
    int*          ck1     = (int*)(ws + WS_CK1);
    float*        cd2     = (float*)(ws + WS_CD2);
    short*        ahi     = (short*)(ws + WS_AHI);
    short*        alo     = (short*)(ws + WS_ALO);
    int*          counter = ((int*)misc) + 1;

    prep_kernel<<<dim3(KKE), dim3(256), 0, stream>>>(emb, embT, bnorm, ehi, elo, hist, misc);
    asplit_kernel<<<dim3(4, BB), dim3(256), 0, stream>>>(inp, ahi, alo, anorm);
    argmin_mfma<<<dim3(4096), dim3(256), 0, stream>>>(ahi, alo, ehi, elo, anorm, bnorm, cd1, ck1, cd2);
    reduce_kernel<<<dim3(256), dim3(256), 0, stream>>>(cd1, ck1, cd2, idx, list, counter);
    rescore_kernel<<<dim3(512), dim3(256), 0, stream>>>(inp, embT, anorm, bnorm, list, counter, idx);
    tail_kernel<<<dim3(ENC_BLK + OL_BLK), dim3(256), 0, stream>>>(inp, embT, idx, out + ENC_OFF, out + OUT_OFF, hist, misc);
    final_kernel<<<dim3(1), dim3(1024), 0, stream>>>(hist, misc, out);
}